// Round 13
// baseline (59.124 us; speedup 1.0000x reference)
//
#include <hip/hip_runtime.h>

typedef __attribute__((ext_vector_type(2))) float f32x2;
typedef __attribute__((ext_vector_type(4))) float f32x4;
typedef __attribute__((ext_vector_type(8))) short bf16x8;
typedef __attribute__((ext_vector_type(4))) unsigned u32x4;
typedef __attribute__((ext_vector_type(2))) unsigned u32x2;

// pack two fp32 -> two bf16 (round-half-up; <=0.5ulp vs RTNE, plenty for our threshold)
// NOTE: pure bit-ops, NO inline asm — R5 showed asm cvt_pk pins registers and spills (m240)
static __device__ __forceinline__ unsigned bfpack(float a, float b) {
    unsigned ua = __builtin_bit_cast(unsigned, a) + 0x8000u;
    unsigned ub = __builtin_bit_cast(unsigned, b) + 0x8000u;
    return (ua >> 16) | (ub & 0xFFFF0000u);
}

#if defined(__has_builtin)
#if __has_builtin(__builtin_amdgcn_exp2f)
#define EXP2F __builtin_amdgcn_exp2f
#endif
#if __has_builtin(__builtin_amdgcn_permlane16_swap) && __has_builtin(__builtin_amdgcn_permlane32_swap)
#define HAVE_PERMLANE_SWAP 1
#endif
#endif
#ifndef EXP2F
#define EXP2F exp2f
#endif

#define VFMA(a, b, c) __builtin_elementwise_fma((a), (b), (c))

// sum x over the 4 lane-groups sharing sl (lanes l, l^16, l^32, l^48), result in all lanes.
// pure VALU (no DS pipe); perf-neutral vs shfl_xor (R12) but spill-free scheduling.
static __device__ __forceinline__ float groupsum(float x) {
#ifdef HAVE_PERMLANE_SWAP
    unsigned u = __builtin_bit_cast(unsigned, x);
    u32x2 a = __builtin_amdgcn_permlane16_swap(u, u, false, false);
    float s = __builtin_bit_cast(float, a[0]) + __builtin_bit_cast(float, a[1]);
    unsigned v = __builtin_bit_cast(unsigned, s);
    u32x2 b = __builtin_amdgcn_permlane32_swap(v, v, false, false);
    return __builtin_bit_cast(float, b[0]) + __builtin_bit_cast(float, b[1]);
#else
    x += __shfl_xor(x, 16);
    x += __shfl_xor(x, 32);
    return x;
#endif
}

// Wave = 16 samples. Lane l: sample sl = l&15, group g = l>>4.
// GEMM per step: Z1[j,s] = sum_k W1[j,k] * U[k,s]  (4 channels, K=64)
//   A = W1: lane holds A[j = sl + 16*tp][k = g*8 + e + 32*c]  (bf16x8 frags, static)
//   B = U : lane holds U[k = g*8 + e + 32*c][sample sl]. No LDS anywhere.
//   C/D  : col = lane&15 (sample), row j = 16*tp + 4*g + r   [m89-verified]
// First MFMA of each chain takes b1 / zero directly as C (no acc-init moves).
// All eval math on f32x2 pairs -> VOP3P v_pk_{fma,mul,add}_f32 (R11: -18%).
// REGISTER BUDGET (R13 theory): VALU-class live set must fit 128 arch VGPRs
// (backend pins 128; R7/R9 spill past it). Constants: p00/p01/p02/tb = 64
// + w2v 16 + working ~46 = ~126 fits. pq[] was the +16 that overflowed ->
// recompute q = p00^2+p01^2 per step (16 pk-inst, ~0.7%) instead of storing it.
__global__ __launch_bounds__(256)
__attribute__((amdgpu_waves_per_eu(2, 2)))
void cnf_kernel(const float* __restrict__ yin,
                const float* __restrict__ eW0, const float* __restrict__ eb0,
                const float* __restrict__ eW1, const float* __restrict__ eb1,
                const float* __restrict__ eW2,
                const float* __restrict__ dW0, const float* __restrict__ db0,
                const float* __restrict__ dW1, const float* __restrict__ db1,
                const float* __restrict__ dW2,
                const int* __restrict__ t1p,
                float* __restrict__ out, int nsamp)
{
    const int lane  = threadIdx.x & 63;
    const int wid   = threadIdx.x >> 6;
    const int wavei = blockIdx.x * 4 + wid;
    const int sl    = lane & 15;   // sample within wave; also A-row base
    const int g     = lane >> 4;   // lane group
    const int s     = wavei * 16 + sl;

    float y1 = yin[2 * s];
    float y2 = yin[2 * s + 1];
    float lp = 0.0f;
    const int t1 = *t1p;

    const f32x4 kzero  = f32x4{0.f, 0.f, 0.f, 0.f};
    const f32x2 ONE2   = f32x2{1.f, 1.f};
    const f32x2 TWO2   = f32x2{2.f, 2.f};
    const f32x2 M2     = f32x2{-2.f, -2.f};
    const f32x2 NL2E   = f32x2{-1.4426950408889634f, -1.4426950408889634f};

    for (int ph = 0; ph < 2; ++ph) {
        const float* W0 = ph ? dW0 : eW0;
        const float* B0 = ph ? db0 : eb0;
        const float* W1 = ph ? dW1 : eW1;
        const float* B1 = ph ? db1 : eb1;
        const float* W2 = ph ? dW2 : eW2;
        const int nsteps = ph ? t1 : 10;

        // ---- static A fragments: W1 tiles in bf16 ----
        bf16x8 afrag[4][2];
        #pragma unroll
        for (int tp = 0; tp < 4; ++tp) {
            #pragma unroll
            for (int c = 0; c < 2; ++c) {
                const float* p = W1 + (sl + 16 * tp) * 64 + g * 8 + 32 * c;
                f32x4 lo = *(const f32x4*)p;
                f32x4 hi = *(const f32x4*)(p + 4);
                u32x4 a;
                a[0] = bfpack(lo[0], lo[1]);
                a[1] = bfpack(lo[2], lo[3]);
                a[2] = bfpack(hi[0], hi[1]);
                a[3] = bfpack(hi[2], hi[3]);
                afrag[tp][c] = __builtin_bit_cast(bf16x8, a);
            }
        }

        // ---- per-lane W0 params for its 16 k's, stored as f32x2 pairs ----
        // pair pi covers k-indices (g*8 + 2*e2 + 32*c, +1); tb = w02*t + b0 incremental
        f32x2 p00[8], p01[8], p02[8], tb[8];
        #pragma unroll
        for (int c = 0; c < 2; ++c) {
            const int kb = g * 8 + 32 * c;
            const float* p = W0 + 3 * kb;          // 24 contiguous floats
            float buf[24];
            #pragma unroll
            for (int q = 0; q < 6; ++q) {
                f32x4 v = ((const f32x4*)p)[q];
                buf[4*q+0] = v[0]; buf[4*q+1] = v[1];
                buf[4*q+2] = v[2]; buf[4*q+3] = v[3];
            }
            #pragma unroll
            for (int e2 = 0; e2 < 4; ++e2) {
                const int pi = c * 4 + e2;
                p00[pi] = f32x2{buf[6*e2 + 0], buf[6*e2 + 3]};
                p01[pi] = f32x2{buf[6*e2 + 1], buf[6*e2 + 4]};
                p02[pi] = f32x2{buf[6*e2 + 2], buf[6*e2 + 5]};
            }
            f32x4 ba = *(const f32x4*)(B0 + kb);
            f32x4 bb = *(const f32x4*)(B0 + kb + 4);
            tb[c*4+0] = f32x2{ba[0], ba[1]};
            tb[c*4+1] = f32x2{ba[2], ba[3]};
            tb[c*4+2] = f32x2{bb[0], bb[1]};
            tb[c*4+3] = f32x2{bb[2], bb[3]};
        }

        // ---- layer-2 params for this lane's 16 j's (j = 16*tp + 4*g + r) ----
        f32x4 b1v[4], w2v[4];
        #pragma unroll
        for (int tp = 0; tp < 4; ++tp) {
            b1v[tp] = *(const f32x4*)(B1 + 16 * tp + 4 * g);
            w2v[tp] = *(const f32x4*)(W2 + 16 * tp + 4 * g);
        }

        for (int n = 0; n < nsteps; ++n) {
            const f32x2 Y1 = f32x2{y1, y1};
            const f32x2 Y2 = f32x2{y2, y2};

            // ---- layer 0: build all B fragments (4 channels), paired evals ----
            bf16x8 Bv[2], Bg1[2], Bg2[2], Bh[2];
            #pragma unroll
            for (int c = 0; c < 2; ++c) {
                u32x4 qv, qg1, qg2, qh;
                #pragma unroll
                for (int e2 = 0; e2 < 4; ++e2) {
                    const int pi = c * 4 + e2;
                    f32x2 z  = VFMA(p00[pi], Y1, VFMA(p01[pi], Y2, tb[pi]));
                    f32x2 zz = z * NL2E;                       // exp(-z) = 2^(z*-log2e)
                    f32x2 ex = f32x2{EXP2F(zz[0]), EXP2F(zz[1])};
                    f32x2 dn = ONE2 + ex;
                    f32x2 sg = f32x2{__builtin_amdgcn_rcpf(dn[0]),
                                     __builtin_amdgcn_rcpf(dn[1])};
                    f32x2 sp = VFMA(-sg, sg, sg);
                    f32x2 s1 = VFMA(z, sp, sg);
                    f32x2 s2 = sp * VFMA(z, VFMA(M2, sg, ONE2), TWO2);
                    f32x2 u0 = z * sg;
                    f32x2 g1 = s1 * p00[pi];
                    f32x2 g2 = s1 * p01[pi];
                    f32x2 q  = VFMA(p00[pi], p00[pi], p01[pi] * p01[pi]); // recomputed (reg diet)
                    f32x2 hh = s2 * q;
                    qv[e2]  = bfpack(u0[0], u0[1]);
                    qg1[e2] = bfpack(g1[0], g1[1]);
                    qg2[e2] = bfpack(g2[0], g2[1]);
                    qh[e2]  = bfpack(hh[0], hh[1]);
                }
                Bv[c]  = __builtin_bit_cast(bf16x8, qv);
                Bg1[c] = __builtin_bit_cast(bf16x8, qg1);
                Bg2[c] = __builtin_bit_cast(bf16x8, qg2);
                Bh[c]  = __builtin_bit_cast(bf16x8, qh);
            }

            // ---- MFMA + epilogue, two j-tile pairs; paired eval math ----
            f32x2 F1 = f32x2{0.f, 0.f}, F2 = f32x2{0.f, 0.f}, TR = f32x2{0.f, 0.f};
            #pragma unroll
            for (int hp = 0; hp < 2; ++hp) {
                f32x4 av[2], ag1[2], ag2[2], ah[2];
                #pragma unroll
                for (int u = 0; u < 2; ++u) {
                    const int tp = hp * 2 + u;
                    // first MFMA of each chain consumes b1 / zero directly as C
                    av[u]  = __builtin_amdgcn_mfma_f32_16x16x32_bf16(afrag[tp][0], Bv[0],  b1v[tp], 0, 0, 0);
                    ag1[u] = __builtin_amdgcn_mfma_f32_16x16x32_bf16(afrag[tp][0], Bg1[0], kzero,   0, 0, 0);
                    ag2[u] = __builtin_amdgcn_mfma_f32_16x16x32_bf16(afrag[tp][0], Bg2[0], kzero,   0, 0, 0);
                    ah[u]  = __builtin_amdgcn_mfma_f32_16x16x32_bf16(afrag[tp][0], Bh[0],  kzero,   0, 0, 0);
                    av[u]  = __builtin_amdgcn_mfma_f32_16x16x32_bf16(afrag[tp][1], Bv[1],  av[u],  0, 0, 0);
                    ag1[u] = __builtin_amdgcn_mfma_f32_16x16x32_bf16(afrag[tp][1], Bg1[1], ag1[u], 0, 0, 0);
                    ag2[u] = __builtin_amdgcn_mfma_f32_16x16x32_bf16(afrag[tp][1], Bg2[1], ag2[u], 0, 0, 0);
                    ah[u]  = __builtin_amdgcn_mfma_f32_16x16x32_bf16(afrag[tp][1], Bh[1],  ah[u],  0, 0, 0);
                }
                #pragma unroll
                for (int u = 0; u < 2; ++u) {
                    const int tp = hp * 2 + u;
                    #pragma unroll
                    for (int rp = 0; rp < 2; ++rp) {
                        // element access (runtime idx OK, const-folded after unroll)
                        f32x2 ZV  = f32x2{av[u][2*rp],  av[u][2*rp+1]};
                        f32x2 ZG1 = f32x2{ag1[u][2*rp], ag1[u][2*rp+1]};
                        f32x2 ZG2 = f32x2{ag2[u][2*rp], ag2[u][2*rp+1]};
                        f32x2 AH  = f32x2{ah[u][2*rp],  ah[u][2*rp+1]};
                        f32x2 W2  = f32x2{w2v[tp][2*rp], w2v[tp][2*rp+1]};

                        f32x2 zz = ZV * NL2E;
                        f32x2 ex = f32x2{EXP2F(zz[0]), EXP2F(zz[1])};
                        f32x2 dn = ONE2 + ex;
                        f32x2 sg = f32x2{__builtin_amdgcn_rcpf(dn[0]),
                                         __builtin_amdgcn_rcpf(dn[1])};
                        f32x2 sp  = VFMA(-sg, sg, sg);
                        f32x2 s1b = VFMA(ZV, sp, sg);
                        f32x2 s2b = sp * VFMA(ZV, VFMA(M2, sg, ONE2), TWO2);
                        f32x2 C1  = W2 * s1b;
                        f32x2 C2  = W2 * s2b;
                        F1 = VFMA(C1, ZG1, F1);
                        F2 = VFMA(C1, ZG2, F2);
                        f32x2 T = VFMA(ZG1, ZG1, ZG2 * ZG2);
                        TR = VFMA(C2, T, VFMA(C1, AH, TR));
                    }
                }
            }
            float f1  = F1[0] + F1[1];
            float f2  = F2[0] + F2[1];
            float trp = TR[0] + TR[1];

            // ---- reduce over the 4 lane groups: pure-VALU permlane (no DS waits) ----
            f1  = groupsum(f1);
            f2  = groupsum(f2);
            trp = groupsum(trp);

            y1 += f1;    // dt = 1.0
            y2 += f2;
            lp += trp;
            #pragma unroll
            for (int i = 0; i < 8; ++i) tb[i] += p02[i];   // t advances by dt=1 (pk adds)
        }
    }

    if (lane < 16) {
        out[2 * s]         = y1;
        out[2 * s + 1]     = y2;
        out[2 * nsamp + s] = lp;
    }
}

extern "C" void kernel_launch(void* const* d_in, const int* in_sizes, int n_in,
                              void* d_out, int out_size, void* d_ws, size_t ws_size,
                              hipStream_t stream)
{
    const float* y   = (const float*)d_in[0];
    const float* eW0 = (const float*)d_in[1];
    const float* eb0 = (const float*)d_in[2];
    const float* eW1 = (const float*)d_in[3];
    const float* eb1 = (const float*)d_in[4];
    const float* eW2 = (const float*)d_in[5];
    // d_in[6] = eb2 (no effect on drift/trace)
    const float* dW0 = (const float*)d_in[7];
    const float* db0 = (const float*)d_in[8];
    const float* dW1 = (const float*)d_in[9];
    const float* db1 = (const float*)d_in[10];
    const float* dW2 = (const float*)d_in[11];
    // d_in[12] = db2 (no effect)
    const int* t1 = (const int*)d_in[13];

    float* out = (float*)d_out;
    const int nsamp = in_sizes[0] / 2;         // 32768
    const int blocks = nsamp / 64;             // 4 waves/block, 16 samples/wave

    cnf_kernel<<<blocks, 256, 0, stream>>>(
        y, eW0, eb0, eW1, eb1, eW2, dW0, db0, dW1, db1, dW2, t1, out, nsamp);
}

// Round 14
// 51.975 us; speedup vs baseline: 1.1375x; 1.1375x over previous
//
#include <hip/hip_runtime.h>

typedef __attribute__((ext_vector_type(2))) float f32x2;
typedef __attribute__((ext_vector_type(4))) float f32x4;
typedef __attribute__((ext_vector_type(8))) short bf16x8;
typedef __attribute__((ext_vector_type(4))) unsigned u32x4;
typedef __attribute__((ext_vector_type(2))) unsigned u32x2;
typedef __attribute__((ext_vector_type(2))) __bf16 bfv2;

// pack two fp32 -> two bf16 via the C-level cast path: clang selects the gfx950
// hardware v_cvt_pk_bf16_f32 (1 inst/pair, RTNE). NO inline asm (R5/m240: asm
// constraints pin registers and spill); NO bit-twiddle (R3-R13: ~5 inst/pair).
static __device__ __forceinline__ unsigned bfpack2(f32x2 v) {
    bfv2 h = __builtin_convertvector(v, bfv2);
    return __builtin_bit_cast(unsigned, h);
}

#if defined(__has_builtin)
#if __has_builtin(__builtin_amdgcn_exp2f)
#define EXP2F __builtin_amdgcn_exp2f
#endif
#if __has_builtin(__builtin_amdgcn_permlane16_swap) && __has_builtin(__builtin_amdgcn_permlane32_swap)
#define HAVE_PERMLANE_SWAP 1
#endif
#endif
#ifndef EXP2F
#define EXP2F exp2f
#endif

#define VFMA(a, b, c) __builtin_elementwise_fma((a), (b), (c))

// sum x over the 4 lane-groups sharing sl (lanes l, l^16, l^32, l^48), result in all lanes.
// pure VALU (no DS pipe); perf-neutral vs shfl_xor (R12) but spill-free scheduling.
static __device__ __forceinline__ float groupsum(float x) {
#ifdef HAVE_PERMLANE_SWAP
    unsigned u = __builtin_bit_cast(unsigned, x);
    u32x2 a = __builtin_amdgcn_permlane16_swap(u, u, false, false);
    float s = __builtin_bit_cast(float, a[0]) + __builtin_bit_cast(float, a[1]);
    unsigned v = __builtin_bit_cast(unsigned, s);
    u32x2 b = __builtin_amdgcn_permlane32_swap(v, v, false, false);
    return __builtin_bit_cast(float, b[0]) + __builtin_bit_cast(float, b[1]);
#else
    x += __shfl_xor(x, 16);
    x += __shfl_xor(x, 32);
    return x;
#endif
}

// Wave = 16 samples. Lane l: sample sl = l&15, group g = l>>4.
// GEMM per step: Z1[j,s] = sum_k W1[j,k] * U[k,s]  (4 channels, K=64)
//   A = W1: lane holds A[j = sl + 16*tp][k = g*8 + e + 32*c]  (bf16x8 frags, static)
//   B = U : lane holds U[k = g*8 + e + 32*c][sample sl]. No LDS anywhere.
//   C/D  : col = lane&15 (sample), row j = 16*tp + 4*g + r   [m89-verified]
// First MFMA of each chain takes b1 / zero directly as C (no acc-init moves).
// All eval math on f32x2 pairs -> VOP3P v_pk_{fma,mul,add}_f32 (R11: -18%).
// bf16 packing via v_cvt_pk_bf16_f32 (R14): 1 inst/pair vs 5, ~20% of VALU stream.
__global__ __launch_bounds__(256)
__attribute__((amdgpu_waves_per_eu(2, 2)))
void cnf_kernel(const float* __restrict__ yin,
                const float* __restrict__ eW0, const float* __restrict__ eb0,
                const float* __restrict__ eW1, const float* __restrict__ eb1,
                const float* __restrict__ eW2,
                const float* __restrict__ dW0, const float* __restrict__ db0,
                const float* __restrict__ dW1, const float* __restrict__ db1,
                const float* __restrict__ dW2,
                const int* __restrict__ t1p,
                float* __restrict__ out, int nsamp)
{
    const int lane  = threadIdx.x & 63;
    const int wid   = threadIdx.x >> 6;
    const int wavei = blockIdx.x * 4 + wid;
    const int sl    = lane & 15;   // sample within wave; also A-row base
    const int g     = lane >> 4;   // lane group
    const int s     = wavei * 16 + sl;

    float y1 = yin[2 * s];
    float y2 = yin[2 * s + 1];
    float lp = 0.0f;
    const int t1 = *t1p;

    const f32x4 kzero  = f32x4{0.f, 0.f, 0.f, 0.f};
    const f32x2 ONE2   = f32x2{1.f, 1.f};
    const f32x2 TWO2   = f32x2{2.f, 2.f};
    const f32x2 M2     = f32x2{-2.f, -2.f};
    const f32x2 NL2E   = f32x2{-1.4426950408889634f, -1.4426950408889634f};

    for (int ph = 0; ph < 2; ++ph) {
        const float* W0 = ph ? dW0 : eW0;
        const float* B0 = ph ? db0 : eb0;
        const float* W1 = ph ? dW1 : eW1;
        const float* B1 = ph ? db1 : eb1;
        const float* W2 = ph ? dW2 : eW2;
        const int nsteps = ph ? t1 : 10;

        // ---- static A fragments: W1 tiles in bf16 ----
        bf16x8 afrag[4][2];
        #pragma unroll
        for (int tp = 0; tp < 4; ++tp) {
            #pragma unroll
            for (int c = 0; c < 2; ++c) {
                const float* p = W1 + (sl + 16 * tp) * 64 + g * 8 + 32 * c;
                f32x4 lo = *(const f32x4*)p;
                f32x4 hi = *(const f32x4*)(p + 4);
                u32x4 a;
                a[0] = bfpack2(f32x2{lo[0], lo[1]});
                a[1] = bfpack2(f32x2{lo[2], lo[3]});
                a[2] = bfpack2(f32x2{hi[0], hi[1]});
                a[3] = bfpack2(f32x2{hi[2], hi[3]});
                afrag[tp][c] = __builtin_bit_cast(bf16x8, a);
            }
        }

        // ---- per-lane W0 params for its 16 k's, stored as f32x2 pairs ----
        // pair pi covers k-indices (g*8 + 2*e2 + 32*c, +1); tb = w02*t + b0 incremental
        f32x2 p00[8], p01[8], p02[8], tb[8];
        #pragma unroll
        for (int c = 0; c < 2; ++c) {
            const int kb = g * 8 + 32 * c;
            const float* p = W0 + 3 * kb;          // 24 contiguous floats
            float buf[24];
            #pragma unroll
            for (int q = 0; q < 6; ++q) {
                f32x4 v = ((const f32x4*)p)[q];
                buf[4*q+0] = v[0]; buf[4*q+1] = v[1];
                buf[4*q+2] = v[2]; buf[4*q+3] = v[3];
            }
            #pragma unroll
            for (int e2 = 0; e2 < 4; ++e2) {
                const int pi = c * 4 + e2;
                p00[pi] = f32x2{buf[6*e2 + 0], buf[6*e2 + 3]};
                p01[pi] = f32x2{buf[6*e2 + 1], buf[6*e2 + 4]};
                p02[pi] = f32x2{buf[6*e2 + 2], buf[6*e2 + 5]};
            }
            f32x4 ba = *(const f32x4*)(B0 + kb);
            f32x4 bb = *(const f32x4*)(B0 + kb + 4);
            tb[c*4+0] = f32x2{ba[0], ba[1]};
            tb[c*4+1] = f32x2{ba[2], ba[3]};
            tb[c*4+2] = f32x2{bb[0], bb[1]};
            tb[c*4+3] = f32x2{bb[2], bb[3]};
        }

        // ---- layer-2 params for this lane's 16 j's (j = 16*tp + 4*g + r) ----
        f32x4 b1v[4], w2v[4];
        #pragma unroll
        for (int tp = 0; tp < 4; ++tp) {
            b1v[tp] = *(const f32x4*)(B1 + 16 * tp + 4 * g);
            w2v[tp] = *(const f32x4*)(W2 + 16 * tp + 4 * g);
        }

        for (int n = 0; n < nsteps; ++n) {
            const f32x2 Y1 = f32x2{y1, y1};
            const f32x2 Y2 = f32x2{y2, y2};

            // ---- layer 0: build all B fragments (4 channels), paired evals ----
            bf16x8 Bv[2], Bg1[2], Bg2[2], Bh[2];
            #pragma unroll
            for (int c = 0; c < 2; ++c) {
                u32x4 qv, qg1, qg2, qh;
                #pragma unroll
                for (int e2 = 0; e2 < 4; ++e2) {
                    const int pi = c * 4 + e2;
                    f32x2 z  = VFMA(p00[pi], Y1, VFMA(p01[pi], Y2, tb[pi]));
                    f32x2 zz = z * NL2E;                       // exp(-z) = 2^(z*-log2e)
                    f32x2 ex = f32x2{EXP2F(zz[0]), EXP2F(zz[1])};
                    f32x2 dn = ONE2 + ex;
                    f32x2 sg = f32x2{__builtin_amdgcn_rcpf(dn[0]),
                                     __builtin_amdgcn_rcpf(dn[1])};
                    f32x2 sp = VFMA(-sg, sg, sg);
                    f32x2 s1 = VFMA(z, sp, sg);
                    f32x2 s2 = sp * VFMA(z, VFMA(M2, sg, ONE2), TWO2);
                    f32x2 u0 = z * sg;
                    f32x2 g1 = s1 * p00[pi];
                    f32x2 g2 = s1 * p01[pi];
                    f32x2 q  = VFMA(p00[pi], p00[pi], p01[pi] * p01[pi]); // recomputed (reg diet)
                    f32x2 hh = s2 * q;
                    qv[e2]  = bfpack2(u0);
                    qg1[e2] = bfpack2(g1);
                    qg2[e2] = bfpack2(g2);
                    qh[e2]  = bfpack2(hh);
                }
                Bv[c]  = __builtin_bit_cast(bf16x8, qv);
                Bg1[c] = __builtin_bit_cast(bf16x8, qg1);
                Bg2[c] = __builtin_bit_cast(bf16x8, qg2);
                Bh[c]  = __builtin_bit_cast(bf16x8, qh);
            }

            // ---- MFMA + epilogue, two j-tile pairs; paired eval math ----
            f32x2 F1 = f32x2{0.f, 0.f}, F2 = f32x2{0.f, 0.f}, TR = f32x2{0.f, 0.f};
            #pragma unroll
            for (int hp = 0; hp < 2; ++hp) {
                f32x4 av[2], ag1[2], ag2[2], ah[2];
                #pragma unroll
                for (int u = 0; u < 2; ++u) {
                    const int tp = hp * 2 + u;
                    // first MFMA of each chain consumes b1 / zero directly as C
                    av[u]  = __builtin_amdgcn_mfma_f32_16x16x32_bf16(afrag[tp][0], Bv[0],  b1v[tp], 0, 0, 0);
                    ag1[u] = __builtin_amdgcn_mfma_f32_16x16x32_bf16(afrag[tp][0], Bg1[0], kzero,   0, 0, 0);
                    ag2[u] = __builtin_amdgcn_mfma_f32_16x16x32_bf16(afrag[tp][0], Bg2[0], kzero,   0, 0, 0);
                    ah[u]  = __builtin_amdgcn_mfma_f32_16x16x32_bf16(afrag[tp][0], Bh[0],  kzero,   0, 0, 0);
                    av[u]  = __builtin_amdgcn_mfma_f32_16x16x32_bf16(afrag[tp][1], Bv[1],  av[u],  0, 0, 0);
                    ag1[u] = __builtin_amdgcn_mfma_f32_16x16x32_bf16(afrag[tp][1], Bg1[1], ag1[u], 0, 0, 0);
                    ag2[u] = __builtin_amdgcn_mfma_f32_16x16x32_bf16(afrag[tp][1], Bg2[1], ag2[u], 0, 0, 0);
                    ah[u]  = __builtin_amdgcn_mfma_f32_16x16x32_bf16(afrag[tp][1], Bh[1],  ah[u],  0, 0, 0);
                }
                #pragma unroll
                for (int u = 0; u < 2; ++u) {
                    const int tp = hp * 2 + u;
                    #pragma unroll
                    for (int rp = 0; rp < 2; ++rp) {
                        // element access (runtime idx OK, const-folded after unroll)
                        f32x2 ZV  = f32x2{av[u][2*rp],  av[u][2*rp+1]};
                        f32x2 ZG1 = f32x2{ag1[u][2*rp], ag1[u][2*rp+1]};
                        f32x2 ZG2 = f32x2{ag2[u][2*rp], ag2[u][2*rp+1]};
                        f32x2 AH  = f32x2{ah[u][2*rp],  ah[u][2*rp+1]};
                        f32x2 W2  = f32x2{w2v[tp][2*rp], w2v[tp][2*rp+1]};

                        f32x2 zz = ZV * NL2E;
                        f32x2 ex = f32x2{EXP2F(zz[0]), EXP2F(zz[1])};
                        f32x2 dn = ONE2 + ex;
                        f32x2 sg = f32x2{__builtin_amdgcn_rcpf(dn[0]),
                                         __builtin_amdgcn_rcpf(dn[1])};
                        f32x2 sp  = VFMA(-sg, sg, sg);
                        f32x2 s1b = VFMA(ZV, sp, sg);
                        f32x2 s2b = sp * VFMA(ZV, VFMA(M2, sg, ONE2), TWO2);
                        f32x2 C1  = W2 * s1b;
                        f32x2 C2  = W2 * s2b;
                        F1 = VFMA(C1, ZG1, F1);
                        F2 = VFMA(C1, ZG2, F2);
                        f32x2 T = VFMA(ZG1, ZG1, ZG2 * ZG2);
                        TR = VFMA(C2, T, VFMA(C1, AH, TR));
                    }
                }
            }
            float f1  = F1[0] + F1[1];
            float f2  = F2[0] + F2[1];
            float trp = TR[0] + TR[1];

            // ---- reduce over the 4 lane groups: pure-VALU permlane (no DS waits) ----
            f1  = groupsum(f1);
            f2  = groupsum(f2);
            trp = groupsum(trp);

            y1 += f1;    // dt = 1.0
            y2 += f2;
            lp += trp;
            #pragma unroll
            for (int i = 0; i < 8; ++i) tb[i] += p02[i];   // t advances by dt=1 (pk adds)
        }
    }

    if (lane < 16) {
        out[2 * s]         = y1;
        out[2 * s + 1]     = y2;
        out[2 * nsamp + s] = lp;
    }
}

extern "C" void kernel_launch(void* const* d_in, const int* in_sizes, int n_in,
                              void* d_out, int out_size, void* d_ws, size_t ws_size,
                              hipStream_t stream)
{
    const float* y   = (const float*)d_in[0];
    const float* eW0 = (const float*)d_in[1];
    const float* eb0 = (const float*)d_in[2];
    const float* eW1 = (const float*)d_in[3];
    const float* eb1 = (const float*)d_in[4];
    const float* eW2 = (const float*)d_in[5];
    // d_in[6] = eb2 (no effect on drift/trace)
    const float* dW0 = (const float*)d_in[7];
    const float* db0 = (const float*)d_in[8];
    const float* dW1 = (const float*)d_in[9];
    const float* db1 = (const float*)d_in[10];
    const float* dW2 = (const float*)d_in[11];
    // d_in[12] = db2 (no effect)
    const int* t1 = (const int*)d_in[13];

    float* out = (float*)d_out;
    const int nsamp = in_sizes[0] / 2;         // 32768
    const int blocks = nsamp / 64;             // 4 waves/block, 16 samples/wave

    cnf_kernel<<<blocks, 256, 0, stream>>>(
        y, eW0, eb0, eW1, eb1, eW2, dW0, db0, dW1, db1, dW2, t1, out, nsamp);
}